// Round 6
// baseline (182.431 us; speedup 1.0000x reference)
//
#include <hip/hip_runtime.h>
#include <stdint.h>

// Problem constants (from reference): B=2, S=4096, D_MODEL=1024, H=16, d_k=64
// RADIUS = ceil(sqrt(4*0.28*ln(1e6))*2) = 8, window = 9 (positions s-8..s)
constexpr int S_LEN = 4096;
constexpr int DM    = 1024;
constexpr int RAD   = 8;
constexpr float INV2T = 1.7857142857142858f; // 1/(2*0.28)

constexpr int BM = 128, BN = 128, BK = 64;   // BK=64: 32 MFMA/barrier (measured: 31.5->38% MfmaUtil)

typedef _Float16 h8v __attribute__((ext_vector_type(8)));  // 8 f16 (4 VGPRs) MFMA frag
typedef float f32x4  __attribute__((ext_vector_type(4)));  // MFMA accumulator

// async global->LDS, 16B/lane. LDS dst is wave-uniform base + lane*16 (HW rule).
static __device__ __forceinline__ void gl_lds16(const void* gp, void* lp) {
  auto g = (const __attribute__((address_space(1))) void*)(uintptr_t)gp;
  auto l = (__attribute__((address_space(3))) void*)(uint32_t)(uintptr_t)lp;
  __builtin_amdgcn_global_load_lds(g, l, 16, 0, 0);
}

// ---------------- prep: x->fp16 cast + 4x W transpose-cast, one launch -------
__global__ __launch_bounds__(256) void sda_prep_kernel(
    const float* __restrict__ X, _Float16* __restrict__ XH,
    const float* __restrict__ W0, const float* __restrict__ W1,
    const float* __restrict__ W2, const float* __restrict__ W3,
    _Float16* __restrict__ T0, _Float16* __restrict__ T1,
    _Float16* __restrict__ T2, _Float16* __restrict__ T3) {
  __shared__ float t[32][33];
  int z = blockIdx.z;
  int tx = threadIdx.x, ty = threadIdx.y;
  if (z < 4) {
    const float* W = z == 0 ? W0 : (z == 1 ? W1 : (z == 2 ? W2 : W3));
    _Float16*    T = z == 0 ? T0 : (z == 1 ? T1 : (z == 2 ? T2 : T3));
    int n0 = blockIdx.x * 32, k0 = blockIdx.y * 32;
#pragma unroll
    for (int i = 0; i < 4; ++i)
      t[ty + 8 * i][tx] = W[(size_t)(k0 + ty + 8 * i) * DM + n0 + tx];
    __syncthreads();
#pragma unroll
    for (int i = 0; i < 4; ++i)
      T[(size_t)(n0 + ty + 8 * i) * DM + k0 + tx] = (_Float16)t[tx][ty + 8 * i];
  } else {
    int blk = (z - 4) * 1024 + blockIdx.y * 32 + blockIdx.x;
    int i = blk * 256 + ty * 32 + tx;
    const float4* x4 = (const float4*)X;
    float4 a = x4[2 * i], b = x4[2 * i + 1];
    float f[8] = {a.x, a.y, a.z, a.w, b.x, b.y, b.z, b.w};
    union { _Float16 h[8]; uint4 v; } o;
#pragma unroll
    for (int j = 0; j < 8; ++j) o.h[j] = (_Float16)f[j];
    ((uint4*)XH)[i] = o.v;
  }
}

// ------- fp16 GEMM, XCD-swizzled, BK=64 (R6-verified: MfmaUtil 38%, conflicts 0) ----
__global__ __launch_bounds__(256) void sda_gemm_qkv_kernel(
    const _Float16* __restrict__ A, const _Float16* __restrict__ Bt,
    _Float16* __restrict__ C0, _Float16* __restrict__ C1,
    _Float16* __restrict__ C2) {
  constexpr int Kd = DM;
  __shared__ __align__(16) _Float16 As[BM * BK];  // 16 KB, 128B rows, chunk-XORed
  __shared__ __align__(16) _Float16 Bs[BN * BK];  // 16 KB

  int blk = blockIdx.x;
  int xcd = blk & 7, slot = blk >> 3;
  int xt = slot >> 3, ys = slot & 7;    // x-major within XCD
  int yt = (xcd << 3) | ys;             // y-stripe per XCD
  int m0 = yt * BM, n0 = xt * BN;

  int tid = threadIdx.x, wid = tid >> 6, lane = tid & 63;
  int srow = lane >> 3;
  int sgk = ((lane & 7) ^ (srow & 7)) * 8;    // XOR-permuted global k-chunk
  int wm = (wid >> 1) * 64, wn = (wid & 1) * 64;
  int fm = lane & 15, fc = lane >> 4;

  f32x4 acc[4][4] = {};

  for (int kt = 0; kt < Kd / BK; ++kt) {
    if (kt) __syncthreads();
    int kk = kt * BK;
    int r0 = wid * 32;
#pragma unroll
    for (int i = 0; i < 4; ++i) {
      gl_lds16(A  + (size_t)(m0 + r0 + i * 8 + srow) * Kd + kk + sgk, &As[(r0 + i * 8) * BK]);
      gl_lds16(Bt + (size_t)(n0 + r0 + i * 8 + srow) * Kd + kk + sgk, &Bs[(r0 + i * 8) * BK]);
    }
    __syncthreads();

#pragma unroll
    for (int ks = 0; ks < 2; ++ks) {
      h8v af[4], bfr[4];
#pragma unroll
      for (int i = 0; i < 4; ++i) {
        int row = wm + i * 16 + fm;
        af[i] = *(const h8v*)&As[row * BK + (((ks * 4 + fc) ^ (row & 7)) * 8)];
      }
#pragma unroll
      for (int j = 0; j < 4; ++j) {
        int row = wn + j * 16 + fm;
        bfr[j] = *(const h8v*)&Bs[row * BK + (((ks * 4 + fc) ^ (row & 7)) * 8)];
      }
#pragma unroll
      for (int i = 0; i < 4; ++i)
#pragma unroll
        for (int j = 0; j < 4; ++j)
          acc[i][j] = __builtin_amdgcn_mfma_f32_16x16x32_f16(af[i], bfr[j], acc[i][j], 0, 0, 0);
    }
  }

  int which = n0 >> 10, nc = n0 & 1023;
  _Float16* Cv = which == 0 ? C0 : (which == 1 ? C1 : C2);

  int rr = (lane >> 4) * 4, cc = lane & 15;
#pragma unroll
  for (int i = 0; i < 4; ++i)
#pragma unroll
    for (int j = 0; j < 4; ++j) {
      size_t base = (size_t)(m0 + wm + i * 16 + rr) * DM + (nc + wn + j * 16 + cc);
#pragma unroll
      for (int r = 0; r < 4; ++r)
        Cv[base + (size_t)r * DM] = (_Float16)acc[i][j][r];
    }
}

// ------- Wo GEMM: proven R6 128x128 structure (512 blocks, ~4 blocks/CU) ----
__global__ __launch_bounds__(256) void sda_gemm_wo_kernel(
    const _Float16* __restrict__ A, const _Float16* __restrict__ Bt,
    float* __restrict__ C) {
  constexpr int Kd = DM;
  __shared__ __align__(16) _Float16 As[BM * BK];
  __shared__ __align__(16) _Float16 Bs[BN * BK];

  int blk = blockIdx.x;
  int xcd = blk & 7, slot = blk >> 3;   // 64 slots/XCD
  int xt = slot >> 3, ys = slot & 7;    // 8 x-tiles, x-major
  int yt = (xcd << 3) | ys;
  int m0 = yt * BM, n0 = xt * BN;

  int tid = threadIdx.x, wid = tid >> 6, lane = tid & 63;
  int srow = lane >> 3;
  int sgk = ((lane & 7) ^ (srow & 7)) * 8;
  int wm = (wid >> 1) * 64, wn = (wid & 1) * 64;
  int fm = lane & 15, fc = lane >> 4;

  f32x4 acc[4][4] = {};

  for (int kt = 0; kt < Kd / BK; ++kt) {
    if (kt) __syncthreads();
    int kk = kt * BK;
    int r0 = wid * 32;
#pragma unroll
    for (int i = 0; i < 4; ++i) {
      gl_lds16(A  + (size_t)(m0 + r0 + i * 8 + srow) * Kd + kk + sgk, &As[(r0 + i * 8) * BK]);
      gl_lds16(Bt + (size_t)(n0 + r0 + i * 8 + srow) * Kd + kk + sgk, &Bs[(r0 + i * 8) * BK]);
    }
    __syncthreads();

#pragma unroll
    for (int ks = 0; ks < 2; ++ks) {
      h8v af[4], bfr[4];
#pragma unroll
      for (int i = 0; i < 4; ++i) {
        int row = wm + i * 16 + fm;
        af[i] = *(const h8v*)&As[row * BK + (((ks * 4 + fc) ^ (row & 7)) * 8)];
      }
#pragma unroll
      for (int j = 0; j < 4; ++j) {
        int row = wn + j * 16 + fm;
        bfr[j] = *(const h8v*)&Bs[row * BK + (((ks * 4 + fc) ^ (row & 7)) * 8)];
      }
#pragma unroll
      for (int i = 0; i < 4; ++i)
#pragma unroll
        for (int j = 0; j < 4; ++j)
          acc[i][j] = __builtin_amdgcn_mfma_f32_16x16x32_f16(af[i], bfr[j], acc[i][j], 0, 0, 0);
    }
  }

  int rr = (lane >> 4) * 4, cc = lane & 15;
#pragma unroll
  for (int i = 0; i < 4; ++i)
#pragma unroll
    for (int j = 0; j < 4; ++j) {
      size_t base = (size_t)(m0 + wm + i * 16 + rr) * DM + (n0 + wn + j * 16 + cc);
#pragma unroll
      for (int r = 0; r < 4; ++r)
        C[base + (size_t)r * DM] = acc[i][j][r];
    }
}

// ---------------- BARRIER-FREE per-wave windowed attention v3 ----------------
// Grid (S/64, B*H), 256 thr = 4 waves. Wave w owns q-rows [16w,16w+16).
// v3: NEITHER K nor V staged in LDS.
//  - QK B-frags: direct global b128 at clamped row p0+t*16+fm (R5-proven).
//  - PV B-frags: element (k=fkg+j, n=t*16+fm) = V[p0+fkg+j][t*16+fm] ->
//    32 global_load_short_d16 per lane, rows clamped to [0,S-1]. Any
//    clamped/out-of-band row k has wt[q][k]==0 (zeroed wt buffer, softmax
//    writes only the 9 band weights), so garbage values contribute 0*finite=0.
//    Each load instruction touches 4 band rows x 32B contiguous - L1/L2-hot.
//    Loads are issued before the softmax so their latency hides under it.
// Removes per wave: 3 predicated uint4 loads + 24 scalar ds_writes + 4
// ds_reads + 2 memory-wait chains; LDS 34 -> 13.25 KB/block.
__global__ __launch_bounds__(256) void sda_attn_kernel(
    const _Float16* __restrict__ Q, const _Float16* __restrict__ K,
    const _Float16* __restrict__ V, _Float16* __restrict__ O) {
  constexpr int WS  = 40;  // wt row stride f16: 80B = 20 dw (<=2-way bank alias)
  __shared__ __align__(16) float    sc[4][16 * 33];   // 2.06 KB/wave
  __shared__ __align__(16) _Float16 wt[4][16 * WS];   // 1.25 KB/wave => 13.25 KB

  int bh = blockIdx.y, b = bh >> 4, h = bh & 15;
  int s0 = blockIdx.x * 64;
  int tid = threadIdx.x, wid = tid >> 6, lane = tid & 63;
  size_t headoff = (size_t)b * S_LEN * DM + h * 64;

  float*    scp = sc[wid];
  _Float16* wtp = wt[wid];

  int p0 = s0 + wid * 16 - RAD;    // first key pos of this wave's 24-key band
  int fm = lane & 15, fkg = (lane >> 4) * 8;
  int rr = (lane >> 4) * 4, cc = lane & 15;

  // zero wt fully (1280 B = 80 x 16B per wave)
  {
    uint4 z = make_uint4(0, 0, 0, 0);
    ((uint4*)wtp)[lane] = z;
    if (lane < 16) ((uint4*)wtp)[64 + lane] = z;
  }

  // Q fragments straight from global (rows always valid)
  const _Float16* qrow = Q + headoff + (size_t)(s0 + wid * 16 + fm) * DM;
  h8v aq0 = *(const h8v*)(qrow + fkg);
  h8v aq1 = *(const h8v*)(qrow + 32 + fkg);

  // ---- QK^T: 2 local key-tiles x K=64, K-frags DIRECT from global ----
  f32x4 accs[2] = {};
#pragma unroll
  for (int t = 0; t < 2; ++t) {
    int pos = p0 + t * 16 + fm;
    int pc = pos < 0 ? 0 : (pos > S_LEN - 1 ? S_LEN - 1 : pos);
    const _Float16* krow = K + headoff + (size_t)pc * DM;
    h8v bk0 = *(const h8v*)(krow + fkg);
    h8v bk1 = *(const h8v*)(krow + 32 + fkg);
    accs[t] = __builtin_amdgcn_mfma_f32_16x16x32_f16(aq0, bk0, accs[t], 0, 0, 0);
    accs[t] = __builtin_amdgcn_mfma_f32_16x16x32_f16(aq1, bk1, accs[t], 0, 0, 0);
  }

  // ---- V fragments DIRECT from global (independent of scores: issue now,
  //      latency hides under score-write + softmax) ----
  h8v bv[4];
  {
    int pos0 = p0 + fkg;
#pragma unroll
    for (int j = 0; j < 8; ++j) {
      int pos = pos0 + j;
      int pc = pos < 0 ? 0 : (pos > S_LEN - 1 ? S_LEN - 1 : pos);
      const _Float16* vrow = V + headoff + (size_t)pc * DM + fm;
#pragma unroll
      for (int t = 0; t < 4; ++t) bv[t][j] = vrow[t * 16];
    }
  }

#pragma unroll
  for (int t = 0; t < 2; ++t)
#pragma unroll
    for (int r = 0; r < 4; ++r)
      scp[(rr + r) * 33 + t * 16 + cc] = accs[t][r];

  // ---- softmax: lane r (0..15) owns q-row r; band cols r..r+8 (< 24) ----
  if (lane < 16) {
    int r = lane, s = s0 + wid * 16 + r;
    const float* my = &scp[r * 33 + r];
    float e[9], mx = -1e30f;
#pragma unroll
    for (int j = 0; j < 9; ++j) {
      float p = my[j] * INV2T;
      e[j] = (s - RAD + j >= 0) ? p : -1e30f;
      mx = fmaxf(mx, e[j]);
    }
    float se = 0.f;
#pragma unroll
    for (int j = 0; j < 9; ++j) { e[j] = __expf(e[j] - mx); se += e[j]; }
    float inv = 1.f / se;
#pragma unroll
    for (int j = 0; j < 9; ++j)
      wtp[r * WS + r + j] = (_Float16)(e[j] * inv);
  }

  // ---- PV: O(16x64) = wt(16x32) @ V(32x64); one K=32 MFMA per n-tile ----
  f32x4 acco[4] = {};
  h8v aw = *(const h8v*)&wtp[fm * WS + fkg];
#pragma unroll
  for (int t = 0; t < 4; ++t)
    acco[t] = __builtin_amdgcn_mfma_f32_16x16x32_f16(aw, bv[t], acco[t], 0, 0, 0);
#pragma unroll
  for (int t = 0; t < 4; ++t)
#pragma unroll
    for (int r = 0; r < 4; ++r)
      O[headoff + (size_t)(s0 + wid * 16 + rr + r) * DM + t * 16 + cc] =
          (_Float16)acco[t][r];
}

extern "C" void kernel_launch(void* const* d_in, const int* in_sizes, int n_in,
                              void* d_out, int out_size, void* d_ws, size_t ws_size,
                              hipStream_t stream) {
  (void)in_sizes; (void)n_in; (void)out_size; (void)ws_size;
  const float* x  = (const float*)d_in[0];
  const float* Wq = (const float*)d_in[1];
  const float* Wk = (const float*)d_in[2];
  const float* Wv = (const float*)d_in[3];
  const float* Wo = (const float*)d_in[4];

  char* ws = (char*)d_ws;
  const size_t MB = 1ull << 20;
  _Float16* xh    = (_Float16*)(ws + 0);        // 16 MB
  _Float16* WqkvT = (_Float16*)(ws + 16 * MB);  // 6 MB: Wq^T|Wk^T|Wv^T
  _Float16* WoT   = (_Float16*)(ws + 22 * MB);  // 2 MB
  _Float16* Qh    = (_Float16*)(ws + 24 * MB);  // 16 MB each
  _Float16* Kh    = (_Float16*)(ws + 40 * MB);
  _Float16* Vh    = (_Float16*)(ws + 56 * MB);
  _Float16* Ah    = (_Float16*)(ws + 72 * MB);  // total 88 MB

  sda_prep_kernel<<<dim3(32, 32, 8), dim3(32, 8), 0, stream>>>(
      x, xh, Wq, Wk, Wv, Wo,
      WqkvT, WqkvT + (size_t)DM * DM, WqkvT + 2ull * DM * DM, WoT);

  // QKV fused: M=8192, N=3072 -> 1536 blocks (1D, XCD-swizzled)
  sda_gemm_qkv_kernel<<<1536, 256, 0, stream>>>(xh, WqkvT, Qh, Kh, Vh);
  sda_attn_kernel<<<dim3(64, 32), 256, 0, stream>>>(Qh, Kh, Vh, Ah);
  // Wo: 128x128 -> 512 blocks
  sda_gemm_wo_kernel<<<512, 256, 0, stream>>>(Ah, WoT, (float*)d_out);
}